// Round 1
// baseline (690.511 us; speedup 1.0000x reference)
//
#include <hip/hip_runtime.h>

#define Bn 2
#define Nn 256
#define Dn 128

__device__ __forceinline__ float sigm(float x) { return 1.0f / (1.0f + expf(-x)); }

// ---------------------------------------------------------------------------
// K1: fused LN1 + 5 projections.
// One block = 32 consecutive rows (all share b and i; j varies).
// Phase A: wave-per-row LN (4 waves x 8 rows). Phase B: 256 threads compute
// 5 GEMVs per row, weights streamed from L2 (coalesced, amortized over 32 rows).
// Writes left, right to ws; og (sigmoid gate) parked in d_out.
// ---------------------------------------------------------------------------
__global__ __launch_bounds__(256) void k1_proj(
    const float* __restrict__ x, const int* __restrict__ msk,
    const float* __restrict__ g1, const float* __restrict__ b1,
    const float* __restrict__ Wl, const float* __restrict__ bl,
    const float* __restrict__ Wr, const float* __restrict__ br,
    const float* __restrict__ Wlg, const float* __restrict__ blg,
    const float* __restrict__ Wrg, const float* __restrict__ brg,
    const float* __restrict__ Wog, const float* __restrict__ bog,
    float* __restrict__ left, float* __restrict__ right, float* __restrict__ og)
{
    __shared__ float xn_s[32][Dn];
    __shared__ float mask_s[32];
    const int tid = threadIdx.x;
    const int wave = tid >> 6, lane = tid & 63;
    const long base = (long)blockIdx.x * 32;

    #pragma unroll
    for (int rr = 0; rr < 8; ++rr) {
        const int r = wave * 8 + rr;
        const long row = base + r;
        const float* xr = x + row * Dn;
        float a0 = xr[lane], a1 = xr[lane + 64];
        float s = a0 + a1, sq = a0 * a0 + a1 * a1;
        #pragma unroll
        for (int m = 1; m < 64; m <<= 1) { s += __shfl_xor(s, m); sq += __shfl_xor(sq, m); }
        float mean = s * (1.0f / 128.0f);
        float var  = sq * (1.0f / 128.0f) - mean * mean;
        float rstd = rsqrtf(var + 1e-5f);
        xn_s[r][lane]      = (a0 - mean) * rstd * g1[lane]      + b1[lane];
        xn_s[r][lane + 64] = (a1 - mean) * rstd * g1[lane + 64] + b1[lane + 64];
        if (lane == 0) {
            int b  = (int)(row >> 16);        // row / (N*N), N*N = 65536
            int rem = (int)(row & 65535);
            int i = rem >> 8, j = rem & 255;
            mask_s[r] = (float)msk[b * Nn + i] * (float)msk[b * Nn + j];
        }
    }
    __syncthreads();

    const int d = tid & 127, half = tid >> 7;
    const int r0 = half * 16;
    float al[16], ar[16], alg[16], arg_[16], aog[16];
    #pragma unroll
    for (int r = 0; r < 16; ++r) { al[r] = ar[r] = alg[r] = arg_[r] = aog[r] = 0.0f; }

    for (int k = 0; k < Dn; ++k) {
        float wl  = Wl [k * Dn + d], wr  = Wr [k * Dn + d];
        float wlg = Wlg[k * Dn + d], wrg = Wrg[k * Dn + d];
        float wog = Wog[k * Dn + d];
        #pragma unroll
        for (int r = 0; r < 16; ++r) {
            float xv = xn_s[r0 + r][k];   // broadcast within wave
            al[r]   += xv * wl;  ar[r]   += xv * wr;
            alg[r]  += xv * wlg; arg_[r] += xv * wrg;
            aog[r]  += xv * wog;
        }
    }
    float blv = bl[d], brv = br[d], blgv = blg[d], brgv = brg[d], bogv = bog[d];
    #pragma unroll
    for (int r = 0; r < 16; ++r) {
        long row = base + r0 + r;
        float mk = mask_s[r0 + r];
        left [row * Dn + d] = (al[r] + blv) * mk * sigm(alg[r]  + blgv);
        right[row * Dn + d] = (ar[r] + brv) * mk * sigm(arg_[r] + brgv);
        og   [row * Dn + d] = sigm(aog[r] + bogv);
    }
}

// ---------------------------------------------------------------------------
// K2: triangle einsum + LN2 + out-gate + final GEMM, fused.
// Block computes an 8(i) x 8(j) x 128(d) output tile, k staged in LDS chunks
// of 8. Then LN2 over d per (i,j) row (wave-per-row shuffle reduce), gate by
// og (read from d_out), and the [64x128]@[128x128] epilogue GEMM, writing the
// final result in place over og in d_out.
// ---------------------------------------------------------------------------
__global__ __launch_bounds__(256) void k2_tri(
    const float* __restrict__ left, const float* __restrict__ right,
    const float* __restrict__ g2, const float* __restrict__ b2,
    const float* __restrict__ Wo, const float* __restrict__ bo,
    float* __restrict__ out /* holds og on entry */)
{
    __shared__ float l_s[8][8][Dn];   // 32 KB: left [k][tj][d]
    __shared__ float r_s[8][8][Dn];   // 32 KB: right[k][ti][d]
    const int tid = threadIdx.x;
    const int b = blockIdx.z;
    const int i0 = blockIdx.y * 8, j0 = blockIdx.x * 8;
    const int d = tid & 127, half = tid >> 7;

    float acc[4][8];
    #pragma unroll
    for (int a = 0; a < 4; ++a)
        #pragma unroll
        for (int t = 0; t < 8; ++t) acc[a][t] = 0.0f;

    for (int k0 = 0; k0 < Nn; k0 += 8) {
        __syncthreads();
        #pragma unroll
        for (int it = 0; it < 8; ++it) {
            int fi = it * 256 + tid;              // 0..2047 float4 slots
            int d4 = fi & 31, t = (fi >> 5) & 7, k = fi >> 8;
            long rl = (((long)b * Nn + k0 + k) * Nn + j0 + t) * Dn + d4 * 4;
            long rr = (((long)b * Nn + k0 + k) * Nn + i0 + t) * Dn + d4 * 4;
            *(float4*)&l_s[k][t][d4 * 4] = *(const float4*)(left  + rl);
            *(float4*)&r_s[k][t][d4 * 4] = *(const float4*)(right + rr);
        }
        __syncthreads();
        #pragma unroll
        for (int k = 0; k < 8; ++k) {
            float rv[4], lv[8];
            #pragma unroll
            for (int a = 0; a < 4; ++a) rv[a] = r_s[k][half * 4 + a][d];
            #pragma unroll
            for (int t = 0; t < 8; ++t) lv[t] = l_s[k][t][d];
            #pragma unroll
            for (int a = 0; a < 4; ++a)
                #pragma unroll
                for (int t = 0; t < 8; ++t) acc[a][t] += rv[a] * lv[t];
        }
    }
    __syncthreads();

    // stage accumulators for LN2: ln_s[pair p = ti*8+tj][d], reusing l_s
    float (*ln_s)[Dn] = (float(*)[Dn])l_s;
    #pragma unroll
    for (int a = 0; a < 4; ++a)
        #pragma unroll
        for (int t = 0; t < 8; ++t)
            ln_s[(half * 4 + a) * 8 + t][d] = acc[a][t];
    __syncthreads();

    // LN2 + og gate: 4 waves x 16 rows, full-wave shuffle reduce
    const int wave = tid >> 6, lane = tid & 63;
    #pragma unroll
    for (int rr = 0; rr < 16; ++rr) {
        int p = wave * 16 + rr;
        float v0 = ln_s[p][lane], v1 = ln_s[p][lane + 64];
        float s = v0 + v1, sq = v0 * v0 + v1 * v1;
        #pragma unroll
        for (int m = 1; m < 64; m <<= 1) { s += __shfl_xor(s, m); sq += __shfl_xor(sq, m); }
        float mean = s * (1.0f / 128.0f);
        float var  = sq * (1.0f / 128.0f) - mean * mean;
        float rstd = rsqrtf(var + 1e-5f);
        int ti = p >> 3, tj = p & 7;
        long gr = (((long)b * Nn + i0 + ti) * Nn + j0 + tj) * Dn;
        float o0 = out[gr + lane], o1 = out[gr + lane + 64];   // og
        ln_s[p][lane]      = ((v0 - mean) * rstd * g2[lane]      + b2[lane])      * o0;
        ln_s[p][lane + 64] = ((v1 - mean) * rstd * g2[lane + 64] + b2[lane + 64]) * o1;
    }
    __syncthreads();

    // epilogue GEMM: out_row = (ln*og) @ Wo + bo
    float acc2[32];
    #pragma unroll
    for (int q = 0; q < 32; ++q) acc2[q] = 0.0f;
    for (int din = 0; din < Dn; ++din) {
        float w = Wo[din * Dn + d];
        #pragma unroll
        for (int q = 0; q < 32; ++q) acc2[q] += ln_s[half * 32 + q][din] * w;
    }
    float bov = bo[d];
    #pragma unroll
    for (int q = 0; q < 32; ++q) {
        int p = half * 32 + q;
        int ti = p >> 3, tj = p & 7;
        long gr = (((long)b * Nn + i0 + ti) * Nn + j0 + tj) * Dn;
        out[gr + d] = acc2[q] + bov;
    }
}

extern "C" void kernel_launch(void* const* d_in, const int* in_sizes, int n_in,
                              void* d_out, int out_size, void* d_ws, size_t ws_size,
                              hipStream_t stream)
{
    const float* x   = (const float*)d_in[0];
    const int*   msk = (const int*)  d_in[1];
    const float* g1  = (const float*)d_in[2];
    const float* b1  = (const float*)d_in[3];
    const float* Wl  = (const float*)d_in[4];
    const float* bl  = (const float*)d_in[5];
    const float* Wr  = (const float*)d_in[6];
    const float* br  = (const float*)d_in[7];
    const float* Wlg = (const float*)d_in[8];
    const float* blg = (const float*)d_in[9];
    const float* Wrg = (const float*)d_in[10];
    const float* brg = (const float*)d_in[11];
    const float* Wog = (const float*)d_in[12];
    const float* bog = (const float*)d_in[13];
    const float* g2  = (const float*)d_in[14];
    const float* b2  = (const float*)d_in[15];
    const float* Wo  = (const float*)d_in[16];
    const float* bo  = (const float*)d_in[17];

    float* out   = (float*)d_out;
    float* left  = (float*)d_ws;                               // 64 MB
    float* right = left + (size_t)Bn * Nn * Nn * Dn;           // 64 MB

    // K1: 131072 rows / 32 rows-per-block
    hipLaunchKernelGGL(k1_proj, dim3(Bn * Nn * Nn / 32), dim3(256), 0, stream,
                       x, msk, g1, b1, Wl, bl, Wr, br, Wlg, blg, Wrg, brg,
                       Wog, bog, left, right, out);
    // K2: (j-tiles, i-tiles, b)
    hipLaunchKernelGGL(k2_tri, dim3(Nn / 8, Nn / 8, Bn), dim3(256), 0, stream,
                       left, right, g2, b2, Wo, bo, out);
}

// Round 3
// 317.293 us; speedup vs baseline: 2.1763x; 2.1763x over previous
//
#include <hip/hip_runtime.h>
#include <stdint.h>

#define Bn 2
#define Nn 256
#define Dn 128

typedef __attribute__((ext_vector_type(8))) short short8;
typedef __attribute__((ext_vector_type(4))) float f32x4;

__device__ __forceinline__ float sigm(float x){ return 1.0f/(1.0f+expf(-x)); }
__device__ __forceinline__ unsigned short f2b(float f){
    unsigned u = __float_as_uint(f);
    return (unsigned short)((u + 0x7FFFu + ((u>>16)&1u)) >> 16);
}
__device__ __forceinline__ float b2f(unsigned short h){
    return __uint_as_float(((unsigned)h)<<16);
}

// ---------------------------------------------------------------------------
// K0: W[k][n] fp32 -> WT[mat][n][k] bf16 (k-contiguous for B-fragments)
// mats: 0=Wl 1=Wr 2=Wlg 3=Wrg 4=Wog 5=Wo
// ---------------------------------------------------------------------------
__global__ __launch_bounds__(256) void k0_wt(
    const float* __restrict__ Wl, const float* __restrict__ Wr,
    const float* __restrict__ Wlg, const float* __restrict__ Wrg,
    const float* __restrict__ Wog, const float* __restrict__ Wo,
    unsigned short* __restrict__ WT)
{
    int mat = blockIdx.x >> 3, kb = blockIdx.x & 7;
    const float* W = (mat==0)?Wl:(mat==1)?Wr:(mat==2)?Wlg:(mat==3)?Wrg:(mat==4)?Wog:Wo;
    int t = threadIdx.x;
    int n = t & 127, kh = t >> 7;
    int k0 = kb*16 + kh*8;
    short8 sv;
    #pragma unroll
    for (int e=0;e<8;++e) sv[e] = (short)f2b(W[(k0+e)*128 + n]);
    *(short8*)&WT[(mat*128 + n)*128 + k0] = sv;
}

// ---------------------------------------------------------------------------
// K1: LN1 + 5 projections via MFMA.  Block = 32 rows (b, p0..p0+32, q fixed),
// k-spanning so left/right are stored k-innermost:
//   leftT [b][q=j][n=d][p=k] bf16,  rightT[b][q=i][n=d][p=k] bf16
// og (sigmoid out-gate) parked fp32 in d_out.
// ---------------------------------------------------------------------------
__global__ __launch_bounds__(256, 3) void k1_proj(
    const float* __restrict__ x, const int* __restrict__ msk,
    const float* __restrict__ g1, const float* __restrict__ b1,
    const unsigned short* __restrict__ WT,
    const float* __restrict__ bl, const float* __restrict__ br,
    const float* __restrict__ blg, const float* __restrict__ brg,
    const float* __restrict__ bog,
    unsigned short* __restrict__ leftT, unsigned short* __restrict__ rightT,
    float* __restrict__ og)
{
    __shared__ __align__(16) unsigned short xn_s[32][160];
    __shared__ __align__(16) unsigned short lds_l[128][36];
    __shared__ __align__(16) unsigned short lds_r[128][36];
    __shared__ __align__(16) float og_s[32][132];
    __shared__ float mask_s[32];

    const int tid = threadIdx.x;
    const int wv = tid>>6, lane = tid&63;
    int bid = blockIdx.x;
    int pb  = bid & 7;
    int q   = (bid >> 3) & 255;
    int b   = bid >> 11;
    int p0  = pb * 32;

    #pragma unroll
    for (int rr=0; rr<8; ++rr){
        int r = wv*8 + rr;
        long row = ((long)(b*Nn + p0 + r))*Nn + q;
        const float* xr = x + row*Dn;
        float a0 = xr[lane], a1 = xr[lane+64];
        float s = a0+a1, sq = a0*a0 + a1*a1;
        #pragma unroll
        for (int m=1; m<64; m<<=1){ s += __shfl_xor(s,m); sq += __shfl_xor(sq,m); }
        float mean = s*(1.f/128.f);
        float var  = sq*(1.f/128.f) - mean*mean;
        float rstd = rsqrtf(var + 1e-5f);
        xn_s[r][lane]    = f2b((a0-mean)*rstd*g1[lane]    + b1[lane]);
        xn_s[r][lane+64] = f2b((a1-mean)*rstd*g1[lane+64] + b1[lane+64]);
        if (lane==0)
            mask_s[r] = (float)(msk[b*Nn + p0 + r] * msk[b*Nn + q]);
    }
    __syncthreads();

    const int l15 = lane & 15, g = lane >> 4;
    const int it = wv >> 1, nh = wv & 1;

    short8 aF[4];
    #pragma unroll
    for (int kc=0; kc<4; ++kc)
        aF[kc] = *(const short8*)&xn_s[it*16 + l15][kc*32 + g*8];

    f32x4 acc[5][4];
    #pragma unroll
    for (int wi=0; wi<5; ++wi){
        #pragma unroll
        for (int nt=0; nt<4; ++nt){
            int n0 = nh*64 + nt*16;
            f32x4 c = {0.f,0.f,0.f,0.f};
            #pragma unroll
            for (int kc=0; kc<4; ++kc){
                short8 bF = *(const short8*)&WT[(wi*128 + n0 + l15)*128 + kc*32 + g*8];
                c = __builtin_amdgcn_mfma_f32_16x16x32_bf16(aF[kc], bF, c, 0,0,0);
            }
            acc[wi][nt] = c;
        }
    }

    #pragma unroll
    for (int nt=0; nt<4; ++nt){
        int n = nh*64 + nt*16 + l15;
        float blv = bl[n], brv = br[n], blgv = blg[n], brgv = brg[n], bogv = bog[n];
        unsigned short pl[4], pr[4];
        #pragma unroll
        for (int r=0; r<4; ++r){
            int prow = it*16 + g*4 + r;
            float mk = mask_s[prow];
            float lv = (acc[0][nt][r] + blv)*mk * sigm(acc[2][nt][r] + blgv);
            float rv = (acc[1][nt][r] + brv)*mk * sigm(acc[3][nt][r] + brgv);
            float ov = sigm(acc[4][nt][r] + bogv);
            pl[r] = f2b(lv); pr[r] = f2b(rv);
            og_s[prow][n] = ov;
        }
        int pbase = it*16 + g*4;
        *(ushort4*)&lds_l[n][pbase] = make_ushort4(pl[0],pl[1],pl[2],pl[3]);
        *(ushort4*)&lds_r[n][pbase] = make_ushort4(pr[0],pr[1],pr[2],pr[3]);
    }
    __syncthreads();

    {
        int n = tid >> 1, h = tid & 1;
        long gbase = (((long)(b*Nn + q))*Dn + n)*Nn + p0 + h*16;
        union { ushort4 u4[4]; short8 s8[2]; } pk;
        #pragma unroll
        for (int e=0;e<4;++e) pk.u4[e] = *(ushort4*)&lds_l[n][h*16 + e*4];
        *(short8*)&leftT[gbase]   = pk.s8[0];
        *(short8*)&leftT[gbase+8] = pk.s8[1];
        #pragma unroll
        for (int e=0;e<4;++e) pk.u4[e] = *(ushort4*)&lds_r[n][h*16 + e*4];
        *(short8*)&rightT[gbase]   = pk.s8[0];
        *(short8*)&rightT[gbase+8] = pk.s8[1];
    }
    {
        int row = tid >> 3, seg = tid & 7;
        long grow = ((long)(b*Nn + p0 + row))*Nn + q;
        #pragma unroll
        for (int e=0;e<4;++e){
            f32x4 v = *(f32x4*)&og_s[row][seg*16 + e*4];
            *(f32x4*)&og[grow*Dn + seg*16 + e*4] = v;
        }
    }
}

// ---------------------------------------------------------------------------
// K2: triangle einsum via MFMA. Block = 64i x 64j x 8d (one d per wave,
// per-wave-private LDS tiles). Register staging (global->VGPR->ds_write):
// DS ops execute in-order per wave, so the cross-iteration WAR hazard of
// async global_load_lds cannot occur. No barriers in the K-loop.
// Output tri[b][db][i][dd][j] bf16 via XOR-swizzled LDS transpose.
// ---------------------------------------------------------------------------
__global__ __launch_bounds__(512, 2) void k2_tri(
    const unsigned short* __restrict__ leftT, const unsigned short* __restrict__ rightT,
    unsigned short* __restrict__ tri)
{
    __shared__ __align__(16) char smem[65536];
    unsigned short (*l_s)[64][32] = (unsigned short(*)[64][32])smem;            // [8][64][32]
    unsigned short (*r_s)[64][32] = (unsigned short(*)[64][32])(smem + 32768);

    const int tid = threadIdx.x;
    const int wv = tid>>6, lane = tid&63;
    const int j0 = blockIdx.x * 64, i0 = blockIdx.y * 64;
    const int db = blockIdx.z & 15, b = blockIdx.z >> 4;
    const int d  = db*8 + wv;
    const int l15 = lane&15, g = lane>>4;

    // staging geometry: 16B slot s (0..255) -> row s>>2, k-chunk s&3
    long rbaseL[4], rbaseR[4];
    int choff[4];
    #pragma unroll
    for (int jj=0; jj<4; ++jj){
        int slot = jj*64 + lane;
        int row = slot >> 2, ch = slot & 3;
        rbaseL[jj] = ((long)((b*Nn + j0 + row)*Dn + d)) << 8;   // *256 k-els
        rbaseR[jj] = ((long)((b*Nn + i0 + row)*Dn + d)) << 8;
        choff[jj] = ch*8;
    }
    short8* dl = (short8*)&l_s[wv][0][0];
    short8* dr = (short8*)&r_s[wv][0][0];

    f32x4 acc[4][4];
    #pragma unroll
    for (int a=0;a<4;++a)
        #pragma unroll
        for (int c=0;c<4;++c) acc[a][c] = (f32x4){0.f,0.f,0.f,0.f};

    for (int k0 = 0; k0 < Nn; k0 += 32){
        short8 stg[8];
        #pragma unroll
        for (int jj=0; jj<4; ++jj){
            stg[jj]   = *(const short8*)&leftT [rbaseL[jj] + k0 + choff[jj]];
            stg[4+jj] = *(const short8*)&rightT[rbaseR[jj] + k0 + choff[jj]];
        }
        #pragma unroll
        for (int jj=0; jj<4; ++jj){
            int slot = jj*64 + lane;
            dl[slot] = stg[jj];
            dr[slot] = stg[4+jj];
        }
        short8 aF[4];
        #pragma unroll
        for (int jt=0;jt<4;++jt) aF[jt] = *(const short8*)&l_s[wv][jt*16 + l15][g*8];
        #pragma unroll
        for (int it2=0;it2<4;++it2){
            short8 bF = *(const short8*)&r_s[wv][it2*16 + l15][g*8];
            #pragma unroll
            for (int jt=0;jt<4;++jt)
                acc[jt][it2] = __builtin_amdgcn_mfma_f32_16x16x32_bf16(aF[jt], bF, acc[jt][it2], 0,0,0);
        }
    }
    __syncthreads();

    // stage D -> tsb (flat rows (i_loc,dd), 64 j-els, 16B-slot XOR-swizzled by i&7)
    unsigned short* tsb = (unsigned short*)smem;
    #pragma unroll
    for (int jt=0;jt<4;++jt){
        #pragma unroll
        for (int it2=0;it2<4;++it2){
            int iloc = it2*16 + l15;
            int rowid = iloc*8 + wv;
            int slotw = (2*jt + (g>>1)) ^ (iloc & 7);
            ushort4 v = make_ushort4(f2b(acc[jt][it2][0]), f2b(acc[jt][it2][1]),
                                     f2b(acc[jt][it2][2]), f2b(acc[jt][it2][3]));
            *(ushort4*)&tsb[rowid*64 + slotw*8 + (g&1)*4] = v;
        }
    }
    __syncthreads();

    long gb = ((((long)(b*16+db))*Nn + i0)*8)*Nn + j0;
    #pragma unroll
    for (int itr=0; itr<8; ++itr){
        int rowid = itr*64 + (tid>>3);
        int jseg  = tid & 7;
        int i_loc = rowid >> 3;
        short8 val = *(const short8*)&tsb[rowid*64 + ((jseg ^ (i_loc&7))*8)];
        *(short8*)&tri[gb + (long)rowid*Nn + jseg*8] = val;
    }
}

// ---------------------------------------------------------------------------
// K3: LN2 + out-gate + final GEMM (MFMA).  Block = 32 rows (b, i, j0..j0+32).
// og read from d_out, final out written over it in place.
// ---------------------------------------------------------------------------
__global__ __launch_bounds__(256, 3) void k3_out(
    const unsigned short* __restrict__ tri, const float* __restrict__ ogate,
    const float* __restrict__ g2, const float* __restrict__ b2,
    const unsigned short* __restrict__ WoT, const float* __restrict__ bo,
    float* __restrict__ out)
{
    __shared__ __align__(16) unsigned short trn_s[32][136];
    __shared__ __align__(16) unsigned short xn_s[32][160];
    __shared__ __align__(16) float out_s[32][132];

    const int tid = threadIdx.x;
    int bid = blockIdx.x;
    int jb = bid & 7, i = (bid>>3) & 255, b = bid >> 11;
    int j0 = jb*32;

    {
        int dfull = tid >> 1, jh = tid & 1;
        int db = dfull >> 3, dd = dfull & 7;
        long base = ((((long)(b*16+db))*Nn + i)*8 + dd)*Nn + j0 + jh*16;
        union { short8 s8[2]; unsigned short u[16]; } v;
        v.s8[0] = *(const short8*)&tri[base];
        v.s8[1] = *(const short8*)&tri[base+8];
        #pragma unroll
        for (int jj=0;jj<16;++jj) trn_s[jh*16+jj][dfull] = v.u[jj];
    }
    __syncthreads();

    const int wv = tid>>6, lane = tid&63;
    #pragma unroll
    for (int rr=0; rr<8; ++rr){
        int r = wv*8 + rr;
        float v0 = b2f(trn_s[r][lane]), v1 = b2f(trn_s[r][lane+64]);
        float s = v0+v1, sq = v0*v0+v1*v1;
        #pragma unroll
        for (int m=1; m<64; m<<=1){ s += __shfl_xor(s,m); sq += __shfl_xor(sq,m); }
        float mean = s*(1.f/128.f);
        float var  = sq*(1.f/128.f) - mean*mean;
        float rstd = rsqrtf(var + 1e-5f);
        long grow = ((long)(b*Nn + i))*Nn + j0 + r;
        float o0 = ogate[grow*Dn + lane], o1 = ogate[grow*Dn + lane+64];
        xn_s[r][lane]    = f2b(((v0-mean)*rstd*g2[lane]    + b2[lane])   *o0);
        xn_s[r][lane+64] = f2b(((v1-mean)*rstd*g2[lane+64] + b2[lane+64])*o1);
    }
    __syncthreads();

    const int l15 = lane&15, g = lane>>4;
    const int it = wv>>1, nh = wv&1;
    short8 aF[4];
    #pragma unroll
    for (int kc=0; kc<4; ++kc)
        aF[kc] = *(const short8*)&xn_s[it*16 + l15][kc*32 + g*8];
    #pragma unroll
    for (int nt=0; nt<4; ++nt){
        int n0 = nh*64 + nt*16;
        f32x4 c = {0.f,0.f,0.f,0.f};
        #pragma unroll
        for (int kc=0; kc<4; ++kc){
            short8 bF = *(const short8*)&WoT[(n0 + l15)*128 + kc*32 + g*8];
            c = __builtin_amdgcn_mfma_f32_16x16x32_bf16(aF[kc], bF, c, 0,0,0);
        }
        float bov = bo[n0 + l15];
        #pragma unroll
        for (int r=0;r<4;++r)
            out_s[it*16 + g*4 + r][n0 + l15] = c[r] + bov;
    }
    __syncthreads();

    {
        int row = tid>>3, seg = tid&7;
        long grow = ((long)(b*Nn + i))*Nn + j0 + row;
        #pragma unroll
        for (int e=0;e<4;++e){
            f32x4 v = *(f32x4*)&out_s[row][seg*16 + e*4];
            *(f32x4*)&out[grow*Dn + seg*16 + e*4] = v;
        }
    }
}

extern "C" void kernel_launch(void* const* d_in, const int* in_sizes, int n_in,
                              void* d_out, int out_size, void* d_ws, size_t ws_size,
                              hipStream_t stream)
{
    const float* x   = (const float*)d_in[0];
    const int*   msk = (const int*)  d_in[1];
    const float* g1  = (const float*)d_in[2];
    const float* b1  = (const float*)d_in[3];
    const float* Wl  = (const float*)d_in[4];
    const float* bl  = (const float*)d_in[5];
    const float* Wr  = (const float*)d_in[6];
    const float* br  = (const float*)d_in[7];
    const float* Wlg = (const float*)d_in[8];
    const float* blg = (const float*)d_in[9];
    const float* Wrg = (const float*)d_in[10];
    const float* brg = (const float*)d_in[11];
    const float* Wog = (const float*)d_in[12];
    const float* bog = (const float*)d_in[13];
    const float* g2  = (const float*)d_in[14];
    const float* b2  = (const float*)d_in[15];
    const float* Wo  = (const float*)d_in[16];
    const float* bo  = (const float*)d_in[17];

    float* out = (float*)d_out;
    char* wsb = (char*)d_ws;
    unsigned short* leftT  = (unsigned short*)wsb;                    // 32 MB
    unsigned short* rightT = (unsigned short*)(wsb + 33554432);       // 32 MB
    unsigned short* tri    = (unsigned short*)(wsb + 67108864);       // 32 MB
    unsigned short* WT     = (unsigned short*)(wsb + 100663296);      // 6*32 KB
    unsigned short* WoT    = WT + 5*128*128;

    hipLaunchKernelGGL(k0_wt, dim3(48), dim3(256), 0, stream,
                       Wl, Wr, Wlg, Wrg, Wog, Wo, WT);
    hipLaunchKernelGGL(k1_proj, dim3(Bn*Nn*8), dim3(256), 0, stream,
                       x, msk, g1, b1, WT, bl, br, blg, brg, bog,
                       leftT, rightT, out);
    hipLaunchKernelGGL(k2_tri, dim3(4, 4, 32), dim3(512), 0, stream,
                       leftT, rightT, tri);
    hipLaunchKernelGGL(k3_out, dim3(Bn*Nn*8), dim3(256), 0, stream,
                       tri, out, g2, b2, WoT, bo, out);
}

// Round 4
// 237.977 us; speedup vs baseline: 2.9016x; 1.3333x over previous
//
#include <hip/hip_runtime.h>
#include <stdint.h>

#define Bn 2
#define Nn 256
#define Dn 128

typedef __attribute__((ext_vector_type(8))) short short8;
typedef __attribute__((ext_vector_type(4))) float f32x4;

__device__ __forceinline__ float sigm(float x){ return 1.0f/(1.0f+expf(-x)); }
__device__ __forceinline__ unsigned short f2b(float f){
    unsigned u = __float_as_uint(f);
    return (unsigned short)((u + 0x7FFFu + ((u>>16)&1u)) >> 16);
}
__device__ __forceinline__ float b2f(unsigned short h){
    return __uint_as_float(((unsigned)h)<<16);
}

// ---------------------------------------------------------------------------
// K0: W[k][n] fp32 -> WTf in MFMA B-fragment order:
//   frag f = (mat*8 + nt)*4 + kc ; within frag, lane l, elem e holds
//   W[k = kc*32 + (l>>4)*8 + e][n = nt*16 + (l&15)]
// Each fragment is a contiguous 1KB block -> B-loads are single bursts.
// mats: 0=Wl 1=Wr 2=Wlg 3=Wrg 4=Wog 5=Wo
// ---------------------------------------------------------------------------
__global__ __launch_bounds__(256) void k0_wt(
    const float* __restrict__ Wl, const float* __restrict__ Wr,
    const float* __restrict__ Wlg, const float* __restrict__ Wrg,
    const float* __restrict__ Wog, const float* __restrict__ Wo,
    unsigned short* __restrict__ WTf)
{
    int mat = blockIdx.x >> 3, nt = blockIdx.x & 7;
    const float* W = (mat==0)?Wl:(mat==1)?Wr:(mat==2)?Wlg:(mat==3)?Wrg:(mat==4)?Wog:Wo;
    int t = threadIdx.x;
    int kc = t >> 6, l = t & 63;
    int n  = nt*16 + (l & 15);
    int k0 = kc*32 + (l >> 4)*8;
    short8 sv;
    #pragma unroll
    for (int e=0;e<8;++e) sv[e] = (short)f2b(W[(k0+e)*128 + n]);
    *(short8*)&WTf[(((mat*8 + nt)*4 + kc) << 9) + l*8] = sv;
}

// ---------------------------------------------------------------------------
// K1: LN1 + 5 projections via MFMA.  Block = 32 rows (b, p0..p0+32, q fixed),
// k-spanning so left/right are stored k-innermost:
//   leftT [b][q=j][n=d][p=k] bf16,  rightT[b][q=i][n=d][p=k] bf16
// og (sigmoid out-gate) parked fp32 in d_out. B-frags from fragment-ordered
// WTf (contiguous 1KB per load).
// ---------------------------------------------------------------------------
__global__ __launch_bounds__(256, 4) void k1_proj(
    const float* __restrict__ x, const int* __restrict__ msk,
    const float* __restrict__ g1, const float* __restrict__ b1,
    const unsigned short* __restrict__ WTf,
    const float* __restrict__ bl, const float* __restrict__ br,
    const float* __restrict__ blg, const float* __restrict__ brg,
    const float* __restrict__ bog,
    unsigned short* __restrict__ leftT, unsigned short* __restrict__ rightT,
    float* __restrict__ og)
{
    __shared__ __align__(16) unsigned short xn_s[32][160];
    __shared__ __align__(16) unsigned short lds_l[128][36];
    __shared__ __align__(16) unsigned short lds_r[128][36];
    __shared__ __align__(16) unsigned short og_s[32][136];
    __shared__ float mask_s[32];

    const int tid = threadIdx.x;
    const int wv = tid>>6, lane = tid&63;
    int bid = blockIdx.x;
    int pb  = bid & 7;
    int q   = (bid >> 3) & 255;
    int b   = bid >> 11;
    int p0  = pb * 32;

    #pragma unroll
    for (int rr=0; rr<8; ++rr){
        int r = wv*8 + rr;
        long row = ((long)(b*Nn + p0 + r))*Nn + q;
        const float* xr = x + row*Dn;
        float a0 = xr[lane], a1 = xr[lane+64];
        float s = a0+a1, sq = a0*a0 + a1*a1;
        #pragma unroll
        for (int m=1; m<64; m<<=1){ s += __shfl_xor(s,m); sq += __shfl_xor(sq,m); }
        float mean = s*(1.f/128.f);
        float var  = sq*(1.f/128.f) - mean*mean;
        float rstd = rsqrtf(var + 1e-5f);
        xn_s[r][lane]    = f2b((a0-mean)*rstd*g1[lane]    + b1[lane]);
        xn_s[r][lane+64] = f2b((a1-mean)*rstd*g1[lane+64] + b1[lane+64]);
        if (lane==0)
            mask_s[r] = (float)(msk[b*Nn + p0 + r] * msk[b*Nn + q]);
    }
    __syncthreads();

    const int l15 = lane & 15, g = lane >> 4;
    const int it = wv >> 1, nh = wv & 1;

    short8 aF[4];
    #pragma unroll
    for (int kc=0; kc<4; ++kc)
        aF[kc] = *(const short8*)&xn_s[it*16 + l15][kc*32 + g*8];

    f32x4 acc[5][4];
    #pragma unroll
    for (int wi=0; wi<5; ++wi){
        #pragma unroll
        for (int nt=0; nt<4; ++nt){
            f32x4 c = {0.f,0.f,0.f,0.f};
            #pragma unroll
            for (int kc=0; kc<4; ++kc){
                short8 bF = *(const short8*)&WTf[(((wi*8 + nh*4 + nt)*4 + kc) << 9) + lane*8];
                c = __builtin_amdgcn_mfma_f32_16x16x32_bf16(aF[kc], bF, c, 0,0,0);
            }
            acc[wi][nt] = c;
        }
    }

    #pragma unroll
    for (int nt=0; nt<4; ++nt){
        int n = nh*64 + nt*16 + l15;
        float blv = bl[n], brv = br[n], blgv = blg[n], brgv = brg[n], bogv = bog[n];
        unsigned short pl[4], pr[4];
        #pragma unroll
        for (int r=0; r<4; ++r){
            int prow = it*16 + g*4 + r;
            float mk = mask_s[prow];
            float lv = (acc[0][nt][r] + blv)*mk * sigm(acc[2][nt][r] + blgv);
            float rv = (acc[1][nt][r] + brv)*mk * sigm(acc[3][nt][r] + brgv);
            float ov = sigm(acc[4][nt][r] + bogv);
            pl[r] = f2b(lv); pr[r] = f2b(rv);
            og_s[prow][n] = f2b(ov);
        }
        int pbase = it*16 + g*4;
        *(ushort4*)&lds_l[n][pbase] = make_ushort4(pl[0],pl[1],pl[2],pl[3]);
        *(ushort4*)&lds_r[n][pbase] = make_ushort4(pr[0],pr[1],pr[2],pr[3]);
    }
    __syncthreads();

    {
        int n = tid >> 1, h = tid & 1;
        long gbase = (((long)(b*Nn + q))*Dn + n)*Nn + p0 + h*16;
        union { ushort4 u4[4]; short8 s8[2]; } pk;
        #pragma unroll
        for (int e=0;e<4;++e) pk.u4[e] = *(ushort4*)&lds_l[n][h*16 + e*4];
        *(short8*)&leftT[gbase]   = pk.s8[0];
        *(short8*)&leftT[gbase+8] = pk.s8[1];
        #pragma unroll
        for (int e=0;e<4;++e) pk.u4[e] = *(ushort4*)&lds_r[n][h*16 + e*4];
        *(short8*)&rightT[gbase]   = pk.s8[0];
        *(short8*)&rightT[gbase+8] = pk.s8[1];
    }
    {
        int row = tid >> 3, seg = tid & 7;
        long grow = ((long)(b*Nn + p0 + row))*Nn + q;
        #pragma unroll
        for (int e=0;e<4;++e){
            ushort4 u = *(ushort4*)&og_s[row][seg*16 + e*4];
            f32x4 v = { b2f(u.x), b2f(u.y), b2f(u.z), b2f(u.w) };
            *(f32x4*)&og[grow*Dn + seg*16 + e*4] = v;
        }
    }
}

// ---------------------------------------------------------------------------
// K2: triangle einsum via MFMA. Block = 64i x 64j x 8d (one d per wave,
// per-wave-private LDS tiles). Register staging (global->VGPR->ds_write):
// DS ops execute in-order per wave -> no WAR hazard. No K-loop barriers.
// Output tri[b][db][i][dd][j] bf16 via XOR-swizzled LDS transpose.
// ---------------------------------------------------------------------------
__global__ __launch_bounds__(512, 2) void k2_tri(
    const unsigned short* __restrict__ leftT, const unsigned short* __restrict__ rightT,
    unsigned short* __restrict__ tri)
{
    __shared__ __align__(16) char smem[65536];
    unsigned short (*l_s)[64][32] = (unsigned short(*)[64][32])smem;            // [8][64][32]
    unsigned short (*r_s)[64][32] = (unsigned short(*)[64][32])(smem + 32768);

    const int tid = threadIdx.x;
    const int wv = tid>>6, lane = tid&63;
    const int j0 = blockIdx.x * 64, i0 = blockIdx.y * 64;
    const int db = blockIdx.z & 15, b = blockIdx.z >> 4;
    const int d  = db*8 + wv;
    const int l15 = lane&15, g = lane>>4;

    long rbaseL[4], rbaseR[4];
    int choff[4];
    #pragma unroll
    for (int jj=0; jj<4; ++jj){
        int slot = jj*64 + lane;
        int row = slot >> 2, ch = slot & 3;
        rbaseL[jj] = ((long)((b*Nn + j0 + row)*Dn + d)) << 8;
        rbaseR[jj] = ((long)((b*Nn + i0 + row)*Dn + d)) << 8;
        choff[jj] = ch*8;
    }
    short8* dl = (short8*)&l_s[wv][0][0];
    short8* dr = (short8*)&r_s[wv][0][0];

    f32x4 acc[4][4];
    #pragma unroll
    for (int a=0;a<4;++a)
        #pragma unroll
        for (int c=0;c<4;++c) acc[a][c] = (f32x4){0.f,0.f,0.f,0.f};

    for (int k0 = 0; k0 < Nn; k0 += 32){
        short8 stg[8];
        #pragma unroll
        for (int jj=0; jj<4; ++jj){
            stg[jj]   = *(const short8*)&leftT [rbaseL[jj] + k0 + choff[jj]];
            stg[4+jj] = *(const short8*)&rightT[rbaseR[jj] + k0 + choff[jj]];
        }
        #pragma unroll
        for (int jj=0; jj<4; ++jj){
            int slot = jj*64 + lane;
            dl[slot] = stg[jj];
            dr[slot] = stg[4+jj];
        }
        short8 aF[4];
        #pragma unroll
        for (int jt=0;jt<4;++jt) aF[jt] = *(const short8*)&l_s[wv][jt*16 + l15][g*8];
        #pragma unroll
        for (int it2=0;it2<4;++it2){
            short8 bF = *(const short8*)&r_s[wv][it2*16 + l15][g*8];
            #pragma unroll
            for (int jt=0;jt<4;++jt)
                acc[jt][it2] = __builtin_amdgcn_mfma_f32_16x16x32_bf16(aF[jt], bF, acc[jt][it2], 0,0,0);
        }
    }
    __syncthreads();

    unsigned short* tsb = (unsigned short*)smem;
    #pragma unroll
    for (int jt=0;jt<4;++jt){
        #pragma unroll
        for (int it2=0;it2<4;++it2){
            int iloc = it2*16 + l15;
            int rowid = iloc*8 + wv;
            int slotw = (2*jt + (g>>1)) ^ (iloc & 7);
            ushort4 v = make_ushort4(f2b(acc[jt][it2][0]), f2b(acc[jt][it2][1]),
                                     f2b(acc[jt][it2][2]), f2b(acc[jt][it2][3]));
            *(ushort4*)&tsb[rowid*64 + slotw*8 + (g&1)*4] = v;
        }
    }
    __syncthreads();

    long gb = ((((long)(b*16+db))*Nn + i0)*8)*Nn + j0;
    #pragma unroll
    for (int itr=0; itr<8; ++itr){
        int rowid = itr*64 + (tid>>3);
        int jseg  = tid & 7;
        int i_loc = rowid >> 3;
        short8 val = *(const short8*)&tsb[rowid*64 + ((jseg ^ (i_loc&7))*8)];
        *(short8*)&tri[gb + (long)rowid*Nn + jseg*8] = val;
    }
}

// ---------------------------------------------------------------------------
// K3: LN2 + out-gate + final GEMM (MFMA).  Block = 32 rows (b, i, j0..j0+32).
// og read from d_out, final out written over it in place. Wo frags from WTf
// (mat index 5).
// ---------------------------------------------------------------------------
__global__ __launch_bounds__(256, 3) void k3_out(
    const unsigned short* __restrict__ tri, const float* __restrict__ ogate,
    const float* __restrict__ g2, const float* __restrict__ b2,
    const unsigned short* __restrict__ WTf, const float* __restrict__ bo,
    float* __restrict__ out)
{
    __shared__ __align__(16) unsigned short trn_s[32][136];
    __shared__ __align__(16) unsigned short xn_s[32][160];
    __shared__ __align__(16) float out_s[32][132];

    const int tid = threadIdx.x;
    int bid = blockIdx.x;
    int jb = bid & 7, i = (bid>>3) & 255, b = bid >> 11;
    int j0 = jb*32;

    {
        int dfull = tid >> 1, jh = tid & 1;
        int db = dfull >> 3, dd = dfull & 7;
        long base = ((((long)(b*16+db))*Nn + i)*8 + dd)*Nn + j0 + jh*16;
        union { short8 s8[2]; unsigned short u[16]; } v;
        v.s8[0] = *(const short8*)&tri[base];
        v.s8[1] = *(const short8*)&tri[base+8];
        #pragma unroll
        for (int jj=0;jj<16;++jj) trn_s[jh*16+jj][dfull] = v.u[jj];
    }
    __syncthreads();

    const int wv = tid>>6, lane = tid&63;
    #pragma unroll
    for (int rr=0; rr<8; ++rr){
        int r = wv*8 + rr;
        float v0 = b2f(trn_s[r][lane]), v1 = b2f(trn_s[r][lane+64]);
        float s = v0+v1, sq = v0*v0+v1*v1;
        #pragma unroll
        for (int m=1; m<64; m<<=1){ s += __shfl_xor(s,m); sq += __shfl_xor(sq,m); }
        float mean = s*(1.f/128.f);
        float var  = sq*(1.f/128.f) - mean*mean;
        float rstd = rsqrtf(var + 1e-5f);
        long grow = ((long)(b*Nn + i))*Nn + j0 + r;
        float o0 = ogate[grow*Dn + lane], o1 = ogate[grow*Dn + lane+64];
        xn_s[r][lane]    = f2b(((v0-mean)*rstd*g2[lane]    + b2[lane])   *o0);
        xn_s[r][lane+64] = f2b(((v1-mean)*rstd*g2[lane+64] + b2[lane+64])*o1);
    }
    __syncthreads();

    const int l15 = lane&15, g = lane>>4;
    const int it = wv>>1, nh = wv&1;
    short8 aF[4];
    #pragma unroll
    for (int kc=0; kc<4; ++kc)
        aF[kc] = *(const short8*)&xn_s[it*16 + l15][kc*32 + g*8];
    #pragma unroll
    for (int nt=0; nt<4; ++nt){
        int n0 = nh*64 + nt*16;
        f32x4 c = {0.f,0.f,0.f,0.f};
        #pragma unroll
        for (int kc=0; kc<4; ++kc){
            short8 bF = *(const short8*)&WTf[(((40 + nh*4 + nt)*4 + kc) << 9) + lane*8];
            c = __builtin_amdgcn_mfma_f32_16x16x32_bf16(aF[kc], bF, c, 0,0,0);
        }
        float bov = bo[n0 + l15];
        #pragma unroll
        for (int r=0;r<4;++r)
            out_s[it*16 + g*4 + r][n0 + l15] = c[r] + bov;
    }
    __syncthreads();

    {
        int row = tid>>3, seg = tid&7;
        long grow = ((long)(b*Nn + i))*Nn + j0 + row;
        #pragma unroll
        for (int e=0;e<4;++e){
            f32x4 v = *(f32x4*)&out_s[row][seg*16 + e*4];
            *(f32x4*)&out[grow*Dn + seg*16 + e*4] = v;
        }
    }
}

extern "C" void kernel_launch(void* const* d_in, const int* in_sizes, int n_in,
                              void* d_out, int out_size, void* d_ws, size_t ws_size,
                              hipStream_t stream)
{
    const float* x   = (const float*)d_in[0];
    const int*   msk = (const int*)  d_in[1];
    const float* g1  = (const float*)d_in[2];
    const float* b1  = (const float*)d_in[3];
    const float* Wl  = (const float*)d_in[4];
    const float* bl  = (const float*)d_in[5];
    const float* Wr  = (const float*)d_in[6];
    const float* br  = (const float*)d_in[7];
    const float* Wlg = (const float*)d_in[8];
    const float* blg = (const float*)d_in[9];
    const float* Wrg = (const float*)d_in[10];
    const float* brg = (const float*)d_in[11];
    const float* Wog = (const float*)d_in[12];
    const float* bog = (const float*)d_in[13];
    const float* g2  = (const float*)d_in[14];
    const float* b2  = (const float*)d_in[15];
    const float* Wo  = (const float*)d_in[16];
    const float* bo  = (const float*)d_in[17];

    float* out = (float*)d_out;
    char* wsb = (char*)d_ws;
    unsigned short* leftT  = (unsigned short*)wsb;                    // 32 MB
    unsigned short* rightT = (unsigned short*)(wsb + 33554432);       // 32 MB
    unsigned short* tri    = (unsigned short*)(wsb + 67108864);       // 32 MB
    unsigned short* WTf    = (unsigned short*)(wsb + 100663296);      // 192 KB

    hipLaunchKernelGGL(k0_wt, dim3(48), dim3(256), 0, stream,
                       Wl, Wr, Wlg, Wrg, Wog, Wo, WTf);
    hipLaunchKernelGGL(k1_proj, dim3(Bn*Nn*8), dim3(256), 0, stream,
                       x, msk, g1, b1, WTf, bl, br, blg, brg, bog,
                       leftT, rightT, out);
    hipLaunchKernelGGL(k2_tri, dim3(4, 4, 32), dim3(512), 0, stream,
                       leftT, rightT, tri);
    hipLaunchKernelGGL(k3_out, dim3(Bn*Nn*8), dim3(256), 0, stream,
                       tri, out, g2, b2, WTf, bo, out);
}

// Round 5
// 196.432 us; speedup vs baseline: 3.5153x; 1.2115x over previous
//
#include <hip/hip_runtime.h>
#include <stdint.h>

#define Bn 2
#define Nn 256
#define Dn 128

typedef __attribute__((ext_vector_type(8))) short short8;
typedef __attribute__((ext_vector_type(4))) float f32x4;

__device__ __forceinline__ float sigm(float x){ return 1.0f/(1.0f+expf(-x)); }
__device__ __forceinline__ unsigned short f2b(float f){
    unsigned u = __float_as_uint(f);
    return (unsigned short)((u + 0x7FFFu + ((u>>16)&1u)) >> 16);
}
__device__ __forceinline__ float b2f(unsigned short h){
    return __uint_as_float(((unsigned)h)<<16);
}

// ---------------------------------------------------------------------------
// K0: W[k][n] fp32 -> WTf in MFMA B-fragment order:
//   frag f = (mat*8 + nt)*4 + kc ; lane l, elem e holds
//   W[k = kc*32 + (l>>4)*8 + e][n = nt*16 + (l&15)]
// mats: 0=Wl 1=Wr 2=Wlg 3=Wrg 4=Wog 5=Wo
// ---------------------------------------------------------------------------
__global__ __launch_bounds__(256) void k0_wt(
    const float* __restrict__ Wl, const float* __restrict__ Wr,
    const float* __restrict__ Wlg, const float* __restrict__ Wrg,
    const float* __restrict__ Wog, const float* __restrict__ Wo,
    unsigned short* __restrict__ WTf)
{
    int mat = blockIdx.x >> 3, nt = blockIdx.x & 7;
    const float* W = (mat==0)?Wl:(mat==1)?Wr:(mat==2)?Wlg:(mat==3)?Wrg:(mat==4)?Wog:Wo;
    int t = threadIdx.x;
    int kc = t >> 6, l = t & 63;
    int n  = nt*16 + (l & 15);
    int k0 = kc*32 + (l >> 4)*8;
    short8 sv;
    #pragma unroll
    for (int e=0;e<8;++e) sv[e] = (short)f2b(W[(k0+e)*128 + n]);
    *(short8*)&WTf[(((mat*8 + nt)*4 + kc) << 9) + l*8] = sv;
}

// ---------------------------------------------------------------------------
// K1: LN1 + 5 projections via MFMA.  Block = 32 rows (b, p0..p0+32, q fixed),
// 512 threads / 8 waves.  Wave w owns ALL 32 rows x 16 cols (n = w*16..):
//   acc[5 mats][2 row-tiles] = 40 AGPR  -> 5 waves/SIMD occupancy
//   each B-frag load feeds 2 MFMAs      -> half the L2 weight traffic
// og (sigmoid out-gate) stored fp32 directly to d_out (64B-line pattern).
// left/right k-innermost via LDS transpose: leftT[b][q][n][p] bf16.
// ---------------------------------------------------------------------------
__global__ __launch_bounds__(512, 4) void k1_proj(
    const float* __restrict__ x, const int* __restrict__ msk,
    const float* __restrict__ g1, const float* __restrict__ b1,
    const unsigned short* __restrict__ WTf,
    const float* __restrict__ bl, const float* __restrict__ br,
    const float* __restrict__ blg, const float* __restrict__ brg,
    const float* __restrict__ bog,
    unsigned short* __restrict__ leftT, unsigned short* __restrict__ rightT,
    float* __restrict__ og)
{
    __shared__ __align__(16) unsigned short xn_s[32][136];   // pitch 272B: ~2-way banks
    __shared__ __align__(16) unsigned short lds_l[128][40];  // pitch 80B: 16B-aligned reads
    __shared__ __align__(16) unsigned short lds_r[128][40];
    __shared__ float mask_s[32];

    const int tid = threadIdx.x;
    const int wv = tid>>6, lane = tid&63;
    int bid = blockIdx.x;
    int pb  = bid & 7;
    int q   = (bid >> 3) & 255;
    int b   = bid >> 11;
    int p0  = pb * 32;

    // Phase A: LN of 32 rows, 8 waves x 4 rows
    #pragma unroll
    for (int rr=0; rr<4; ++rr){
        int r = wv*4 + rr;
        long row = ((long)(b*Nn + p0 + r))*Nn + q;
        const float* xr = x + row*Dn;
        float a0 = xr[lane], a1 = xr[lane+64];
        float s = a0+a1, sq = a0*a0 + a1*a1;
        #pragma unroll
        for (int m=1; m<64; m<<=1){ s += __shfl_xor(s,m); sq += __shfl_xor(sq,m); }
        float mean = s*(1.f/128.f);
        float var  = sq*(1.f/128.f) - mean*mean;
        float rstd = rsqrtf(var + 1e-5f);
        xn_s[r][lane]    = f2b((a0-mean)*rstd*g1[lane]    + b1[lane]);
        xn_s[r][lane+64] = f2b((a1-mean)*rstd*g1[lane+64] + b1[lane+64]);
        if (lane==0)
            mask_s[r] = (float)(msk[b*Nn + p0 + r] * msk[b*Nn + q]);
    }
    __syncthreads();

    const int l15 = lane & 15, g = lane >> 4;

    // A-frags: 2 row-tiles x 4 k-chunks
    short8 aF[2][4];
    #pragma unroll
    for (int rt=0; rt<2; ++rt)
        #pragma unroll
        for (int kc=0; kc<4; ++kc)
            aF[rt][kc] = *(const short8*)&xn_s[rt*16 + l15][kc*32 + g*8];

    // MFMA: 5 mats x 2 row-tiles, cols n = wv*16 + l15
    f32x4 acc[5][2];
    #pragma unroll
    for (int wi=0; wi<5; ++wi){
        acc[wi][0] = (f32x4){0.f,0.f,0.f,0.f};
        acc[wi][1] = (f32x4){0.f,0.f,0.f,0.f};
        #pragma unroll
        for (int kc=0; kc<4; ++kc){
            short8 bF = *(const short8*)&WTf[(((wi*8 + wv)*4 + kc) << 9) + lane*8];
            acc[wi][0] = __builtin_amdgcn_mfma_f32_16x16x32_bf16(aF[0][kc], bF, acc[wi][0], 0,0,0);
            acc[wi][1] = __builtin_amdgcn_mfma_f32_16x16x32_bf16(aF[1][kc], bF, acc[wi][1], 0,0,0);
        }
    }

    // Epilogue: bias/mask/gates; og direct fp32 store; left/right -> LDS
    {
        int n = wv*16 + l15;
        float blv = bl[n], brv = br[n], blgv = blg[n], brgv = brg[n], bogv = bog[n];
        #pragma unroll
        for (int rt=0; rt<2; ++rt){
            unsigned short pl[4], pr[4];
            #pragma unroll
            for (int r=0; r<4; ++r){
                int prow = rt*16 + g*4 + r;
                float mk = mask_s[prow];
                float lv = (acc[0][rt][r] + blv)*mk * sigm(acc[2][rt][r] + blgv);
                float rv = (acc[1][rt][r] + brv)*mk * sigm(acc[3][rt][r] + brgv);
                float ov = sigm(acc[4][rt][r] + bogv);
                pl[r] = f2b(lv); pr[r] = f2b(rv);
                long grow = ((long)(b*Nn + p0 + prow))*Nn + q;
                og[grow*Dn + n] = ov;   // lanes l15 contiguous: 64B line per g-group
            }
            int pbase = rt*16 + g*4;
            *(ushort4*)&lds_l[n][pbase] = make_ushort4(pl[0],pl[1],pl[2],pl[3]);
            *(ushort4*)&lds_r[n][pbase] = make_ushort4(pr[0],pr[1],pr[2],pr[3]);
        }
    }
    __syncthreads();

    // Phase C: coalesced writeout (4 threads x 16B = 64B per n-row)
    {
        int n = tid >> 2, quad = tid & 3;
        long gbase = (((long)(b*Nn + q))*Dn + n)*Nn + p0 + quad*8;
        *(short8*)&leftT [gbase] = *(const short8*)&lds_l[n][quad*8];
        *(short8*)&rightT[gbase] = *(const short8*)&lds_r[n][quad*8];
    }
}

// ---------------------------------------------------------------------------
// K2: triangle einsum via MFMA. Block = 64i x 64j x 8d (one d per wave,
// per-wave-private LDS tiles). Register staging (global->VGPR->ds_write):
// DS ops execute in-order per wave -> no WAR hazard. No K-loop barriers.
// Output tri[b][db][i][dd][j] bf16 via XOR-swizzled LDS transpose.
// ---------------------------------------------------------------------------
__global__ __launch_bounds__(512, 2) void k2_tri(
    const unsigned short* __restrict__ leftT, const unsigned short* __restrict__ rightT,
    unsigned short* __restrict__ tri)
{
    __shared__ __align__(16) char smem[65536];
    unsigned short (*l_s)[64][32] = (unsigned short(*)[64][32])smem;            // [8][64][32]
    unsigned short (*r_s)[64][32] = (unsigned short(*)[64][32])(smem + 32768);

    const int tid = threadIdx.x;
    const int wv = tid>>6, lane = tid&63;
    const int j0 = blockIdx.x * 64, i0 = blockIdx.y * 64;
    const int db = blockIdx.z & 15, b = blockIdx.z >> 4;
    const int d  = db*8 + wv;
    const int l15 = lane&15, g = lane>>4;

    long rbaseL[4], rbaseR[4];
    int choff[4];
    #pragma unroll
    for (int jj=0; jj<4; ++jj){
        int slot = jj*64 + lane;
        int row = slot >> 2, ch = slot & 3;
        rbaseL[jj] = ((long)((b*Nn + j0 + row)*Dn + d)) << 8;
        rbaseR[jj] = ((long)((b*Nn + i0 + row)*Dn + d)) << 8;
        choff[jj] = ch*8;
    }
    short8* dl = (short8*)&l_s[wv][0][0];
    short8* dr = (short8*)&r_s[wv][0][0];

    f32x4 acc[4][4];
    #pragma unroll
    for (int a=0;a<4;++a)
        #pragma unroll
        for (int c=0;c<4;++c) acc[a][c] = (f32x4){0.f,0.f,0.f,0.f};

    for (int k0 = 0; k0 < Nn; k0 += 32){
        short8 stg[8];
        #pragma unroll
        for (int jj=0; jj<4; ++jj){
            stg[jj]   = *(const short8*)&leftT [rbaseL[jj] + k0 + choff[jj]];
            stg[4+jj] = *(const short8*)&rightT[rbaseR[jj] + k0 + choff[jj]];
        }
        #pragma unroll
        for (int jj=0; jj<4; ++jj){
            int slot = jj*64 + lane;
            dl[slot] = stg[jj];
            dr[slot] = stg[4+jj];
        }
        short8 aF[4];
        #pragma unroll
        for (int jt=0;jt<4;++jt) aF[jt] = *(const short8*)&l_s[wv][jt*16 + l15][g*8];
        #pragma unroll
        for (int it2=0;it2<4;++it2){
            short8 bF = *(const short8*)&r_s[wv][it2*16 + l15][g*8];
            #pragma unroll
            for (int jt=0;jt<4;++jt)
                acc[jt][it2] = __builtin_amdgcn_mfma_f32_16x16x32_bf16(aF[jt], bF, acc[jt][it2], 0,0,0);
        }
    }
    __syncthreads();

    unsigned short* tsb = (unsigned short*)smem;
    #pragma unroll
    for (int jt=0;jt<4;++jt){
        #pragma unroll
        for (int it2=0;it2<4;++it2){
            int iloc = it2*16 + l15;
            int rowid = iloc*8 + wv;
            int slotw = (2*jt + (g>>1)) ^ (iloc & 7);
            ushort4 v = make_ushort4(f2b(acc[jt][it2][0]), f2b(acc[jt][it2][1]),
                                     f2b(acc[jt][it2][2]), f2b(acc[jt][it2][3]));
            *(ushort4*)&tsb[rowid*64 + slotw*8 + (g&1)*4] = v;
        }
    }
    __syncthreads();

    long gb = ((((long)(b*16+db))*Nn + i0)*8)*Nn + j0;
    #pragma unroll
    for (int itr=0; itr<8; ++itr){
        int rowid = itr*64 + (tid>>3);
        int jseg  = tid & 7;
        int i_loc = rowid >> 3;
        short8 val = *(const short8*)&tsb[rowid*64 + ((jseg ^ (i_loc&7))*8)];
        *(short8*)&tri[gb + (long)rowid*Nn + jseg*8] = val;
    }
}

// ---------------------------------------------------------------------------
// K3: LN2 + out-gate + final GEMM (MFMA).  Block = 32 rows (b, i, j0..j0+32).
// og read from d_out, final out written over it in place. Wo frags from WTf
// (mat index 5).
// ---------------------------------------------------------------------------
__global__ __launch_bounds__(256, 3) void k3_out(
    const unsigned short* __restrict__ tri, const float* __restrict__ ogate,
    const float* __restrict__ g2, const float* __restrict__ b2,
    const unsigned short* __restrict__ WTf, const float* __restrict__ bo,
    float* __restrict__ out)
{
    __shared__ __align__(16) unsigned short trn_s[32][136];
    __shared__ __align__(16) unsigned short xn_s[32][160];
    __shared__ __align__(16) float out_s[32][132];

    const int tid = threadIdx.x;
    int bid = blockIdx.x;
    int jb = bid & 7, i = (bid>>3) & 255, b = bid >> 11;
    int j0 = jb*32;

    {
        int dfull = tid >> 1, jh = tid & 1;
        int db = dfull >> 3, dd = dfull & 7;
        long base = ((((long)(b*16+db))*Nn + i)*8 + dd)*Nn + j0 + jh*16;
        union { short8 s8[2]; unsigned short u[16]; } v;
        v.s8[0] = *(const short8*)&tri[base];
        v.s8[1] = *(const short8*)&tri[base+8];
        #pragma unroll
        for (int jj=0;jj<16;++jj) trn_s[jh*16+jj][dfull] = v.u[jj];
    }
    __syncthreads();

    const int wv = tid>>6, lane = tid&63;
    #pragma unroll
    for (int rr=0; rr<8; ++rr){
        int r = wv*8 + rr;
        float v0 = b2f(trn_s[r][lane]), v1 = b2f(trn_s[r][lane+64]);
        float s = v0+v1, sq = v0*v0+v1*v1;
        #pragma unroll
        for (int m=1; m<64; m<<=1){ s += __shfl_xor(s,m); sq += __shfl_xor(sq,m); }
        float mean = s*(1.f/128.f);
        float var  = sq*(1.f/128.f) - mean*mean;
        float rstd = rsqrtf(var + 1e-5f);
        long grow = ((long)(b*Nn + i))*Nn + j0 + r;
        float o0 = ogate[grow*Dn + lane], o1 = ogate[grow*Dn + lane+64];
        xn_s[r][lane]    = f2b(((v0-mean)*rstd*g2[lane]    + b2[lane])   *o0);
        xn_s[r][lane+64] = f2b(((v1-mean)*rstd*g2[lane+64] + b2[lane+64])*o1);
    }
    __syncthreads();

    const int l15 = lane&15, g = lane>>4;
    const int it = wv>>1, nh = wv&1;
    short8 aF[4];
    #pragma unroll
    for (int kc=0; kc<4; ++kc)
        aF[kc] = *(const short8*)&xn_s[it*16 + l15][kc*32 + g*8];
    #pragma unroll
    for (int nt=0; nt<4; ++nt){
        int n0 = nh*64 + nt*16;
        f32x4 c = {0.f,0.f,0.f,0.f};
        #pragma unroll
        for (int kc=0; kc<4; ++kc){
            short8 bF = *(const short8*)&WTf[(((40 + nh*4 + nt)*4 + kc) << 9) + lane*8];
            c = __builtin_amdgcn_mfma_f32_16x16x32_bf16(aF[kc], bF, c, 0,0,0);
        }
        float bov = bo[n0 + l15];
        #pragma unroll
        for (int r=0;r<4;++r)
            out_s[it*16 + g*4 + r][n0 + l15] = c[r] + bov;
    }
    __syncthreads();

    {
        int row = tid>>3, seg = tid&7;
        long grow = ((long)(b*Nn + i))*Nn + j0 + row;
        #pragma unroll
        for (int e=0;e<4;++e){
            f32x4 v = *(f32x4*)&out_s[row][seg*16 + e*4];
            *(f32x4*)&out[grow*Dn + seg*16 + e*4] = v;
        }
    }
}

extern "C" void kernel_launch(void* const* d_in, const int* in_sizes, int n_in,
                              void* d_out, int out_size, void* d_ws, size_t ws_size,
                              hipStream_t stream)
{
    const float* x   = (const float*)d_in[0];
    const int*   msk = (const int*)  d_in[1];
    const float* g1  = (const float*)d_in[2];
    const float* b1  = (const float*)d_in[3];
    const float* Wl  = (const float*)d_in[4];
    const float* bl  = (const float*)d_in[5];
    const float* Wr  = (const float*)d_in[6];
    const float* br  = (const float*)d_in[7];
    const float* Wlg = (const float*)d_in[8];
    const float* blg = (const float*)d_in[9];
    const float* Wrg = (const float*)d_in[10];
    const float* brg = (const float*)d_in[11];
    const float* Wog = (const float*)d_in[12];
    const float* bog = (const float*)d_in[13];
    const float* g2  = (const float*)d_in[14];
    const float* b2  = (const float*)d_in[15];
    const float* Wo  = (const float*)d_in[16];
    const float* bo  = (const float*)d_in[17];

    float* out = (float*)d_out;
    char* wsb = (char*)d_ws;
    unsigned short* leftT  = (unsigned short*)wsb;                    // 32 MB
    unsigned short* rightT = (unsigned short*)(wsb + 33554432);       // 32 MB
    unsigned short* tri    = (unsigned short*)(wsb + 67108864);       // 32 MB
    unsigned short* WTf    = (unsigned short*)(wsb + 100663296);      // 192 KB

    hipLaunchKernelGGL(k0_wt, dim3(48), dim3(256), 0, stream,
                       Wl, Wr, Wlg, Wrg, Wog, Wo, WTf);
    hipLaunchKernelGGL(k1_proj, dim3(Bn*Nn*8), dim3(512), 0, stream,
                       x, msk, g1, b1, WTf, bl, br, blg, brg, bog,
                       leftT, rightT, out);
    hipLaunchKernelGGL(k2_tri, dim3(4, 4, 32), dim3(512), 0, stream,
                       leftT, rightT, tri);
    hipLaunchKernelGGL(k3_out, dim3(Bn*Nn*8), dim3(256), 0, stream,
                       tri, out, g2, b2, WTf, bo, out);
}

// Round 6
// 166.607 us; speedup vs baseline: 4.1446x; 1.1790x over previous
//
#include <hip/hip_runtime.h>
#include <stdint.h>

#define Bn 2
#define Nn 256
#define Dn 128

typedef __attribute__((ext_vector_type(8))) short short8;
typedef __attribute__((ext_vector_type(4))) float f32x4;

__device__ __forceinline__ float sigm(float x){
    return __builtin_amdgcn_rcpf(1.0f + __builtin_amdgcn_exp2f(-1.44269504f*x));
}
__device__ __forceinline__ unsigned short f2b(float f){
    unsigned u = __float_as_uint(f);
    return (unsigned short)((u + 0x7FFFu + ((u>>16)&1u)) >> 16);
}
__device__ __forceinline__ float b2f(unsigned short h){
    return __uint_as_float(((unsigned)h)<<16);
}

// ---------------------------------------------------------------------------
// K0: W[k][n] fp32 -> WTf in MFMA B-fragment order:
//   frag f = (mat*8 + nt)*4 + kc ; lane l, elem e holds
//   W[k = kc*32 + (l>>4)*8 + e][n = nt*16 + (l&15)]
// mats: 0=Wl 1=Wr 2=Wlg 3=Wrg 4=Wog 5=Wo
// ---------------------------------------------------------------------------
__global__ __launch_bounds__(256) void k0_wt(
    const float* __restrict__ Wl, const float* __restrict__ Wr,
    const float* __restrict__ Wlg, const float* __restrict__ Wrg,
    const float* __restrict__ Wog, const float* __restrict__ Wo,
    unsigned short* __restrict__ WTf)
{
    int mat = blockIdx.x >> 3, nt = blockIdx.x & 7;
    const float* W = (mat==0)?Wl:(mat==1)?Wr:(mat==2)?Wlg:(mat==3)?Wrg:(mat==4)?Wog:Wo;
    int t = threadIdx.x;
    int kc = t >> 6, l = t & 63;
    int n  = nt*16 + (l & 15);
    int k0 = kc*32 + (l >> 4)*8;
    short8 sv;
    #pragma unroll
    for (int e=0;e<8;++e) sv[e] = (short)f2b(W[(k0+e)*128 + n]);
    *(short8*)&WTf[(((mat*8 + nt)*4 + kc) << 9) + l*8] = sv;
}

// ---------------------------------------------------------------------------
// K1: LN1 + 5 projections via MFMA.  Block = 32 rows (b, p0..p0+32, q fixed),
// 512 threads / 8 waves, wave w owns all 32 rows x 16 cols (n = w*16..).
// Mat-pair passes {Wl,Wlg} -> {Wr,Wrg} -> {Wog} keep acc at 16 AGPR peak
// (same 20 B-frag loads/wave as before) -> <=85 unified regs -> 3 blocks/CU.
// og stored bf16 in d_out at 512B/row stride (in-place-safe for k3).
// left/right k-innermost: leftT[b][q][n][p] bf16.
// ---------------------------------------------------------------------------
__global__ __launch_bounds__(512, 6) void k1_proj(
    const float* __restrict__ x, const int* __restrict__ msk,
    const float* __restrict__ g1, const float* __restrict__ b1,
    const unsigned short* __restrict__ WTf,
    const float* __restrict__ bl, const float* __restrict__ br,
    const float* __restrict__ blg, const float* __restrict__ brg,
    const float* __restrict__ bog,
    unsigned short* __restrict__ leftT, unsigned short* __restrict__ rightT,
    unsigned short* __restrict__ og)
{
    __shared__ __align__(16) unsigned short xn_s[32][136];
    __shared__ __align__(16) unsigned short lds_l[128][40];
    __shared__ __align__(16) unsigned short lds_r[128][40];
    __shared__ __align__(16) unsigned short og_s[32][136];
    __shared__ float mask_s[32];

    const int tid = threadIdx.x;
    const int wv = tid>>6, lane = tid&63;
    int bid = blockIdx.x;
    int pb  = bid & 7;
    int q   = (bid >> 3) & 255;
    int b   = bid >> 11;
    int p0  = pb * 32;

    // Phase A: LN of 32 rows, 8 waves x 4 rows
    #pragma unroll
    for (int rr=0; rr<4; ++rr){
        int r = wv*4 + rr;
        long row = ((long)(b*Nn + p0 + r))*Nn + q;
        const float* xr = x + row*Dn;
        float a0 = xr[lane], a1 = xr[lane+64];
        float s = a0+a1, sq = a0*a0 + a1*a1;
        #pragma unroll
        for (int m=1; m<64; m<<=1){ s += __shfl_xor(s,m); sq += __shfl_xor(sq,m); }
        float mean = s*(1.f/128.f);
        float var  = sq*(1.f/128.f) - mean*mean;
        float rstd = rsqrtf(var + 1e-5f);
        xn_s[r][lane]    = f2b((a0-mean)*rstd*g1[lane]    + b1[lane]);
        xn_s[r][lane+64] = f2b((a1-mean)*rstd*g1[lane+64] + b1[lane+64]);
        if (lane==0)
            mask_s[r] = (float)(msk[b*Nn + p0 + r] * msk[b*Nn + q]);
    }
    __syncthreads();

    const int l15 = lane & 15, g = lane >> 4;
    const int n = wv*16 + l15;

    // A-frags: 2 row-tiles x 4 k-chunks (held across passes)
    short8 aF[2][4];
    #pragma unroll
    for (int rt=0; rt<2; ++rt)
        #pragma unroll
        for (int kc=0; kc<4; ++kc)
            aF[rt][kc] = *(const short8*)&xn_s[rt*16 + l15][kc*32 + g*8];

    // Pass L: mats 0 (Wl), 2 (Wlg)
    {
        f32x4 aV[2] = {{0.f,0.f,0.f,0.f},{0.f,0.f,0.f,0.f}};
        f32x4 aG[2] = {{0.f,0.f,0.f,0.f},{0.f,0.f,0.f,0.f}};
        #pragma unroll
        for (int kc=0; kc<4; ++kc){
            short8 bF = *(const short8*)&WTf[(((0*8 + wv)*4 + kc) << 9) + lane*8];
            aV[0] = __builtin_amdgcn_mfma_f32_16x16x32_bf16(aF[0][kc], bF, aV[0], 0,0,0);
            aV[1] = __builtin_amdgcn_mfma_f32_16x16x32_bf16(aF[1][kc], bF, aV[1], 0,0,0);
        }
        #pragma unroll
        for (int kc=0; kc<4; ++kc){
            short8 bF = *(const short8*)&WTf[(((2*8 + wv)*4 + kc) << 9) + lane*8];
            aG[0] = __builtin_amdgcn_mfma_f32_16x16x32_bf16(aF[0][kc], bF, aG[0], 0,0,0);
            aG[1] = __builtin_amdgcn_mfma_f32_16x16x32_bf16(aF[1][kc], bF, aG[1], 0,0,0);
        }
        float bv = bl[n], bgv = blg[n];
        #pragma unroll
        for (int rt=0; rt<2; ++rt){
            unsigned short pk[4];
            #pragma unroll
            for (int r=0; r<4; ++r){
                float mk = mask_s[rt*16 + g*4 + r];
                pk[r] = f2b((aV[rt][r] + bv)*mk * sigm(aG[rt][r] + bgv));
            }
            *(ushort4*)&lds_l[n][rt*16 + g*4] = make_ushort4(pk[0],pk[1],pk[2],pk[3]);
        }
    }
    // Pass R: mats 1 (Wr), 3 (Wrg)
    {
        f32x4 aV[2] = {{0.f,0.f,0.f,0.f},{0.f,0.f,0.f,0.f}};
        f32x4 aG[2] = {{0.f,0.f,0.f,0.f},{0.f,0.f,0.f,0.f}};
        #pragma unroll
        for (int kc=0; kc<4; ++kc){
            short8 bF = *(const short8*)&WTf[(((1*8 + wv)*4 + kc) << 9) + lane*8];
            aV[0] = __builtin_amdgcn_mfma_f32_16x16x32_bf16(aF[0][kc], bF, aV[0], 0,0,0);
            aV[1] = __builtin_amdgcn_mfma_f32_16x16x32_bf16(aF[1][kc], bF, aV[1], 0,0,0);
        }
        #pragma unroll
        for (int kc=0; kc<4; ++kc){
            short8 bF = *(const short8*)&WTf[(((3*8 + wv)*4 + kc) << 9) + lane*8];
            aG[0] = __builtin_amdgcn_mfma_f32_16x16x32_bf16(aF[0][kc], bF, aG[0], 0,0,0);
            aG[1] = __builtin_amdgcn_mfma_f32_16x16x32_bf16(aF[1][kc], bF, aG[1], 0,0,0);
        }
        float bv = br[n], bgv = brg[n];
        #pragma unroll
        for (int rt=0; rt<2; ++rt){
            unsigned short pk[4];
            #pragma unroll
            for (int r=0; r<4; ++r){
                float mk = mask_s[rt*16 + g*4 + r];
                pk[r] = f2b((aV[rt][r] + bv)*mk * sigm(aG[rt][r] + bgv));
            }
            *(ushort4*)&lds_r[n][rt*16 + g*4] = make_ushort4(pk[0],pk[1],pk[2],pk[3]);
        }
    }
    // Pass G: mat 4 (Wog) -> og_s
    {
        f32x4 aV[2] = {{0.f,0.f,0.f,0.f},{0.f,0.f,0.f,0.f}};
        #pragma unroll
        for (int kc=0; kc<4; ++kc){
            short8 bF = *(const short8*)&WTf[(((4*8 + wv)*4 + kc) << 9) + lane*8];
            aV[0] = __builtin_amdgcn_mfma_f32_16x16x32_bf16(aF[0][kc], bF, aV[0], 0,0,0);
            aV[1] = __builtin_amdgcn_mfma_f32_16x16x32_bf16(aF[1][kc], bF, aV[1], 0,0,0);
        }
        float bgv = bog[n];
        #pragma unroll
        for (int rt=0; rt<2; ++rt)
            #pragma unroll
            for (int r=0; r<4; ++r)
                og_s[rt*16 + g*4 + r][n] = f2b(sigm(aV[rt][r] + bgv));
    }
    __syncthreads();

    // Phase C: coalesced writeouts
    {
        int nn = tid >> 2, quad = tid & 3;
        long gbase = (((long)(b*Nn + q))*Dn + nn)*Nn + p0 + quad*8;
        *(short8*)&leftT [gbase] = *(const short8*)&lds_l[nn][quad*8];
        *(short8*)&rightT[gbase] = *(const short8*)&lds_r[nn][quad*8];
    }
    {
        int row = tid >> 4, seg = tid & 15;   // 32 rows x 16 segs x 16B
        long grow = ((long)(b*Nn + p0 + row))*Nn + q;
        *(short8*)&og[grow*256 + seg*8] = *(const short8*)&og_s[row][seg*8];
    }
}

// ---------------------------------------------------------------------------
// K2: triangle einsum via MFMA. Block = 64i x 64j x 8d (one d per wave,
// per-wave-private LDS tiles). Register staging (global->VGPR->ds_write):
// DS ops execute in-order per wave -> no WAR hazard. No K-loop barriers.
// Output tri[b][db][i][dd][j] bf16 via XOR-swizzled LDS transpose.
// ---------------------------------------------------------------------------
__global__ __launch_bounds__(512, 2) void k2_tri(
    const unsigned short* __restrict__ leftT, const unsigned short* __restrict__ rightT,
    unsigned short* __restrict__ tri)
{
    __shared__ __align__(16) char smem[65536];
    unsigned short (*l_s)[64][32] = (unsigned short(*)[64][32])smem;            // [8][64][32]
    unsigned short (*r_s)[64][32] = (unsigned short(*)[64][32])(smem + 32768);

    const int tid = threadIdx.x;
    const int wv = tid>>6, lane = tid&63;
    const int j0 = blockIdx.x * 64, i0 = blockIdx.y * 64;
    const int db = blockIdx.z & 15, b = blockIdx.z >> 4;
    const int d  = db*8 + wv;
    const int l15 = lane&15, g = lane>>4;

    long rbaseL[4], rbaseR[4];
    int choff[4];
    #pragma unroll
    for (int jj=0; jj<4; ++jj){
        int slot = jj*64 + lane;
        int row = slot >> 2, ch = slot & 3;
        rbaseL[jj] = ((long)((b*Nn + j0 + row)*Dn + d)) << 8;
        rbaseR[jj] = ((long)((b*Nn + i0 + row)*Dn + d)) << 8;
        choff[jj] = ch*8;
    }
    short8* dl = (short8*)&l_s[wv][0][0];
    short8* dr = (short8*)&r_s[wv][0][0];

    f32x4 acc[4][4];
    #pragma unroll
    for (int a=0;a<4;++a)
        #pragma unroll
        for (int c=0;c<4;++c) acc[a][c] = (f32x4){0.f,0.f,0.f,0.f};

    for (int k0 = 0; k0 < Nn; k0 += 32){
        short8 stg[8];
        #pragma unroll
        for (int jj=0; jj<4; ++jj){
            stg[jj]   = *(const short8*)&leftT [rbaseL[jj] + k0 + choff[jj]];
            stg[4+jj] = *(const short8*)&rightT[rbaseR[jj] + k0 + choff[jj]];
        }
        #pragma unroll
        for (int jj=0; jj<4; ++jj){
            int slot = jj*64 + lane;
            dl[slot] = stg[jj];
            dr[slot] = stg[4+jj];
        }
        short8 aF[4];
        #pragma unroll
        for (int jt=0;jt<4;++jt) aF[jt] = *(const short8*)&l_s[wv][jt*16 + l15][g*8];
        #pragma unroll
        for (int it2=0;it2<4;++it2){
            short8 bF = *(const short8*)&r_s[wv][it2*16 + l15][g*8];
            #pragma unroll
            for (int jt=0;jt<4;++jt)
                acc[jt][it2] = __builtin_amdgcn_mfma_f32_16x16x32_bf16(aF[jt], bF, acc[jt][it2], 0,0,0);
        }
    }
    __syncthreads();

    unsigned short* tsb = (unsigned short*)smem;
    #pragma unroll
    for (int jt=0;jt<4;++jt){
        #pragma unroll
        for (int it2=0;it2<4;++it2){
            int iloc = it2*16 + l15;
            int rowid = iloc*8 + wv;
            int slotw = (2*jt + (g>>1)) ^ (iloc & 7);
            ushort4 v = make_ushort4(f2b(acc[jt][it2][0]), f2b(acc[jt][it2][1]),
                                     f2b(acc[jt][it2][2]), f2b(acc[jt][it2][3]));
            *(ushort4*)&tsb[rowid*64 + slotw*8 + (g&1)*4] = v;
        }
    }
    __syncthreads();

    long gb = ((((long)(b*16+db))*Nn + i0)*8)*Nn + j0;
    #pragma unroll
    for (int itr=0; itr<8; ++itr){
        int rowid = itr*64 + (tid>>3);
        int jseg  = tid & 7;
        int i_loc = rowid >> 3;
        short8 val = *(const short8*)&tsb[rowid*64 + ((jseg ^ (i_loc&7))*8)];
        *(short8*)&tri[gb + (long)rowid*Nn + jseg*8] = val;
    }
}

// ---------------------------------------------------------------------------
// K3: LN2 + out-gate + final GEMM (MFMA).  Block = 32 rows (b, i, j0..j0+32).
// og read bf16 from d_out (512B/row stride), final out written over it
// in place (same rows, read-before-write, barrier-ordered).
// ---------------------------------------------------------------------------
__global__ __launch_bounds__(256, 3) void k3_out(
    const unsigned short* __restrict__ tri, const unsigned short* __restrict__ ogu,
    const float* __restrict__ g2, const float* __restrict__ b2,
    const unsigned short* __restrict__ WTf, const float* __restrict__ bo,
    float* __restrict__ out)
{
    __shared__ __align__(16) unsigned short trn_s[32][136];
    __shared__ __align__(16) unsigned short xn_s[32][160];
    __shared__ __align__(16) float out_s[32][132];

    const int tid = threadIdx.x;
    int bid = blockIdx.x;
    int jb = bid & 7, i = (bid>>3) & 255, b = bid >> 11;
    int j0 = jb*32;

    {
        int dfull = tid >> 1, jh = tid & 1;
        int db = dfull >> 3, dd = dfull & 7;
        long base = ((((long)(b*16+db))*Nn + i)*8 + dd)*Nn + j0 + jh*16;
        union { short8 s8[2]; unsigned short u[16]; } v;
        v.s8[0] = *(const short8*)&tri[base];
        v.s8[1] = *(const short8*)&tri[base+8];
        #pragma unroll
        for (int jj=0;jj<16;++jj) trn_s[jh*16+jj][dfull] = v.u[jj];
    }
    __syncthreads();

    const int wv = tid>>6, lane = tid&63;
    #pragma unroll
    for (int rr=0; rr<8; ++rr){
        int r = wv*8 + rr;
        float v0 = b2f(trn_s[r][lane]), v1 = b2f(trn_s[r][lane+64]);
        float s = v0+v1, sq = v0*v0+v1*v1;
        #pragma unroll
        for (int m=1; m<64; m<<=1){ s += __shfl_xor(s,m); sq += __shfl_xor(sq,m); }
        float mean = s*(1.f/128.f);
        float var  = sq*(1.f/128.f) - mean*mean;
        float rstd = rsqrtf(var + 1e-5f);
        long grow = ((long)(b*Nn + i))*Nn + j0 + r;
        float o0 = b2f(ogu[grow*256 + lane]);
        float o1 = b2f(ogu[grow*256 + lane + 64]);
        xn_s[r][lane]    = f2b(((v0-mean)*rstd*g2[lane]    + b2[lane])   *o0);
        xn_s[r][lane+64] = f2b(((v1-mean)*rstd*g2[lane+64] + b2[lane+64])*o1);
    }
    __syncthreads();

    const int l15 = lane&15, g = lane>>4;
    const int it = wv>>1, nh = wv&1;
    short8 aF[4];
    #pragma unroll
    for (int kc=0; kc<4; ++kc)
        aF[kc] = *(const short8*)&xn_s[it*16 + l15][kc*32 + g*8];
    #pragma unroll
    for (int nt=0; nt<4; ++nt){
        int n0 = nh*64 + nt*16;
        f32x4 c = {0.f,0.f,0.f,0.f};
        #pragma unroll
        for (int kc=0; kc<4; ++kc){
            short8 bF = *(const short8*)&WTf[(((40 + nh*4 + nt)*4 + kc) << 9) + lane*8];
            c = __builtin_amdgcn_mfma_f32_16x16x32_bf16(aF[kc], bF, c, 0,0,0);
        }
        float bov = bo[n0 + l15];
        #pragma unroll
        for (int r=0;r<4;++r)
            out_s[it*16 + g*4 + r][n0 + l15] = c[r] + bov;
    }
    __syncthreads();

    {
        int row = tid>>3, seg = tid&7;
        long grow = ((long)(b*Nn + i))*Nn + j0 + row;
        #pragma unroll
        for (int e=0;e<4;++e){
            f32x4 v = *(f32x4*)&out_s[row][seg*16 + e*4];
            *(f32x4*)&out[grow*Dn + seg*16 + e*4] = v;
        }
    }
}

extern "C" void kernel_launch(void* const* d_in, const int* in_sizes, int n_in,
                              void* d_out, int out_size, void* d_ws, size_t ws_size,
                              hipStream_t stream)
{
    const float* x   = (const float*)d_in[0];
    const int*   msk = (const int*)  d_in[1];
    const float* g1  = (const float*)d_in[2];
    const float* b1  = (const float*)d_in[3];
    const float* Wl  = (const float*)d_in[4];
    const float* bl  = (const float*)d_in[5];
    const float* Wr  = (const float*)d_in[6];
    const float* br  = (const float*)d_in[7];
    const float* Wlg = (const float*)d_in[8];
    const float* blg = (const float*)d_in[9];
    const float* Wrg = (const float*)d_in[10];
    const float* brg = (const float*)d_in[11];
    const float* Wog = (const float*)d_in[12];
    const float* bog = (const float*)d_in[13];
    const float* g2  = (const float*)d_in[14];
    const float* b2  = (const float*)d_in[15];
    const float* Wo  = (const float*)d_in[16];
    const float* bo  = (const float*)d_in[17];

    float* out = (float*)d_out;
    unsigned short* ogu = (unsigned short*)d_out;   // bf16 gate @ 512B/row stride
    char* wsb = (char*)d_ws;
    unsigned short* leftT  = (unsigned short*)wsb;                    // 32 MB
    unsigned short* rightT = (unsigned short*)(wsb + 33554432);       // 32 MB
    unsigned short* tri    = (unsigned short*)(wsb + 67108864);       // 32 MB
    unsigned short* WTf    = (unsigned short*)(wsb + 100663296);      // 192 KB

    hipLaunchKernelGGL(k0_wt, dim3(48), dim3(256), 0, stream,
                       Wl, Wr, Wlg, Wrg, Wog, Wo, WTf);
    hipLaunchKernelGGL(k1_proj, dim3(Bn*Nn*8), dim3(512), 0, stream,
                       x, msk, g1, b1, WTf, bl, br, blg, brg, bog,
                       leftT, rightT, ogu);
    hipLaunchKernelGGL(k2_tri, dim3(4, 4, 32), dim3(512), 0, stream,
                       leftT, rightT, tri);
    hipLaunchKernelGGL(k3_out, dim3(Bn*Nn*8), dim3(256), 0, stream,
                       tri, ogu, g2, b2, WTf, bo, out);
}